// Round 6
// baseline (219.649 us; speedup 1.0000x reference)
//
#include <hip/hip_runtime.h>
#include <hip/hip_bf16.h>
#include <stdint.h>

// ---------------------------------------------------------------------------
// LinkPredictor: out = minmax_norm(E @ E^T)[block-diag strict upper triangle]
// N=16384 (128 graphs x 128), D=512.
// R16: occupancy doubling. R10/R14/R15 all ~93-97us, MfmaUtil ~32%, every
// pipe idle, Occupancy ~16% -> latency-bound, NOT schedule-bound (issue-early
// null R14, counted-vmcnt+setprio null R15). Root cause: acc[2][2][2] = 128
// AGPR + 120 VGPR = 248 combined (unified file) -> 2 waves/SIMD hard cap.
// Fix: ONE 128x128 tile per block (acc 64 AGPR), __launch_bounds__(256,4)
// -> combined <=128 regs -> 4 waves/SIMD, 4 blocks/CU (LDS 32KB/block).
// Grid: wrapped-column map over x in 0..63: tc=(tr+1+x)&127, (a,b)=minmax --
// all 8128 upper tiles, 64 dup slots, ZERO empty slots; same 65(+pad)x128
// grid and ipart indexing; refine decodes the same map (single tile/slot).
// i8 LDS layout = R14's (conflict-free both sides, measured 0):
//   granule(row,c4) = qswap(row)*4 + (c4 ^ sfun(row)).
// K-loop: plain 2-phase issue-early (schedule variants measured equivalent).
// Diag/convert/gather unchanged.
// ---------------------------------------------------------------------------

typedef __attribute__((ext_vector_type(8))) __bf16 bf16x8;
typedef __attribute__((ext_vector_type(16))) float floatx16;
typedef __attribute__((ext_vector_type(4))) int intx4;
typedef __attribute__((ext_vector_type(16))) int intx16;

#define AS1 __attribute__((address_space(1)))
#define AS3 __attribute__((address_space(3)))

static constexpr int DIM      = 512;
static constexpr int NTILE    = 128;
static constexpr int GX       = 72;         // padded grid x (multiple of 8)
static constexpr int NPAIRIDX = 65 * 128;   // slot space (x=64 -> diag)
static constexpr float QS     = 19.5f;      // i8 quant scale
static constexpr int MARGIN_I = 3042;       // 8 sims-units * QS^2

// ctrl: [0] fkey_min [1] fkey_max [2] i8 gmin

static __device__ __forceinline__ unsigned short f2bf_rne(float f) {
  unsigned int u = __float_as_uint(f);
  u += 0x7fffu + ((u >> 16) & 1u);
  return (unsigned short)(u >> 16);
}
static __device__ __forceinline__ int fkey(float f) {
  int s = __float_as_int(f);
  return s >= 0 ? s : (s ^ 0x7fffffff);
}
static __device__ __forceinline__ float funkey(int k) {
  return __int_as_float(k >= 0 ? k : (k ^ 0x7fffffff));
}
// bf16 tile, BK=128 (diag): 16 chunks(16B)/row
static __device__ __forceinline__ int swzd(int row, int c16) {
  return c16 ^ (row & 15);
}
// bf16 tile, BK=64 (refine): 8 chunks(16B)/row
static __device__ __forceinline__ int swz8(int row, int c8) {
  return c8 ^ (row & 7);
}
// i8 BK=64 layout helpers: q = swap bits 0,2 (involution)
static __device__ __forceinline__ int qswap(int v) {
  return (v & 0x7A) | ((v & 1) << 2) | ((v >> 2) & 1);
}
static __device__ __forceinline__ int sfun(int row) {
  return (row & 3) ^ ((row >> 3) & 3);
}

// ---- kernel 1: fp32 -> bf16 + i8, init ctrl --------------------------------
__global__ void k_convert(const float* __restrict__ in,
                          unsigned short* __restrict__ bf,
                          char* __restrict__ q,
                          int* __restrict__ ctrl, int n4) {
  int i = blockIdx.x * blockDim.x + threadIdx.x;
  if (i == 0) {
    ctrl[0] = 0x7fffffff; ctrl[1] = (int)0x80000000;
    ctrl[2] = 0x7fffffff;
  }
  if (i >= n4) return;
  float4 v = ((const float4*)in)[i];
  ushort4 o;
  o.x = f2bf_rne(v.x); o.y = f2bf_rne(v.y);
  o.z = f2bf_rne(v.z); o.w = f2bf_rne(v.w);
  ((ushort4*)bf)[i] = o;
  int qx = __float2int_rn(v.x * QS), qy = __float2int_rn(v.y * QS);
  int qz = __float2int_rn(v.z * QS), qw = __float2int_rn(v.w * QS);
  char4 c;
  c.x = (char)min(127, max(-127, qx));
  c.y = (char)min(127, max(-127, qy));
  c.z = (char)min(127, max(-127, qz));
  c.w = (char)min(127, max(-127, qw));
  ((char4*)q)[i] = c;
}

// ---- kernel 2: GEMM --------------------------------------------------------
// grid (72, 128): x<64 -> i8 single tile (a,b) via wrapped-column map;
// x==64 -> bf16 exact diagonal tile tr; x>64 -> padding, exit.
__global__ __launch_bounds__(256, 4) void k_gemm(
    const char* __restrict__ Eq,
    const unsigned short* __restrict__ E,
    int* __restrict__ ipart,
    float* __restrict__ diagblocks,
    int* __restrict__ ctrl) {
  const int x  = blockIdx.x;
  const int tr = blockIdx.y;
  if (x > 64) return;                      // XCD-alignment padding
  const int pi = tr * 65 + x;

  const int tid = threadIdx.x;
  // i8 path: 2 buffers x {A[8KB], B[8KB]} = 32 KB.
  // Diag path reuses all 32 KB as one bf16 tile.
  __shared__ __align__(16) char smem[2][16384];
  __shared__ float2 redbuf[4];
  __shared__ int iredbuf[4];

  const int w = tid >> 6, lane = tid & 63;
  const int wr = w >> 1, wc = w & 1;
  const int l31 = lane & 31;
  const int kg  = lane >> 5;

  if (x < 64) {
    // wrapped-column tile map: covers all strictly-upper (a,b); 64 dup slots
    const int tcw = (tr + 1 + x) & 127;
    const int a = min(tr, tcw), b = max(tr, tcw);
    const int rowA = a * 128;
    const int rowB = b * 128;

    intx16 acc[2][2];                // 64 AGPR
#pragma unroll
    for (int i = 0; i < 2; i++)
#pragma unroll
      for (int j = 0; j < 2; j++)
#pragma unroll
        for (int r = 0; r < 16; r++) acc[i][j][r] = 0;

    // Stage one BK=64 K-tile (A,B) into buffer bb: 4 loads/thread.
    // LDS dest linear (p*16). Granule p = qswap(row)*4 + (c4 ^ sfun(row)):
    //   quad q_ = p>>2 -> row = qswap(q_) (involution), c4 = (p&3)^sfun(row).
    // Lanes 4k..4k+3 share a row -> one 64B global line per quad (coalesced);
    // bank-group signature = R10's measured-zero pattern on the read side.
#define STAGE4(bb, kt) do {                                                   \
    _Pragma("unroll")                                                         \
    for (int jj_ = 0; jj_ < 2; jj_++) {                                       \
      int p_   = jj_ * 256 + tid;                                             \
      int q_   = p_ >> 2;                                                     \
      int row_ = qswap(q_);                                                   \
      int off_ = (kt) * 64 + (((p_ & 3) ^ sfun(row_)) * 16);                  \
      char* d_ = smem[bb] + p_ * 16;                                          \
      __builtin_amdgcn_global_load_lds(                                       \
          (const AS1 unsigned int*)(Eq + (size_t)(rowA + row_) * DIM + off_), \
          (AS3 unsigned int*)d_, 16, 0, 0);                                   \
      __builtin_amdgcn_global_load_lds(                                       \
          (const AS1 unsigned int*)(Eq + (size_t)(rowB + row_) * DIM + off_), \
          (AS3 unsigned int*)(d_ + 8192), 16, 0, 0);                          \
    }                                                                         \
  } while (0)

    const int ra0 = wr * 64 + l31,  ra1 = wr * 64 + 32 + l31;
    const int rb0 = wc * 64 + l31,  rb1 = wc * 64 + 32 + l31;
    // per-thread read offsets: byte addr = qswap(row)*64 + ((c4^sfun(row))<<4)
    const int pa0 = qswap(ra0) * 64, sa0 = sfun(ra0);
    const int pa1 = qswap(ra1) * 64, sa1 = sfun(ra1);
    const int pb0 = qswap(rb0) * 64, sb0 = sfun(rb0);
    const int pb1 = qswap(rb1) * 64, sb1 = sfun(rb1);

    STAGE4(0, 0);
    __syncthreads();

#pragma unroll
    for (int kt = 0; kt < 8; kt++) {               // K = 512 = 8 * BK(64)
      // Issue next tile's loads FIRST - they fly during this tile's compute.
      if (kt + 1 < 8) STAGE4((kt + 1) & 1, kt + 1);
      const char* cb = smem[kt & 1];
#pragma unroll
      for (int ks = 0; ks < 2; ks++) {             // 2 k-steps of 32
        const int c = ks * 2 + kg;
        intx4 af0 = *(const intx4*)(cb +        pa0 + ((c ^ sa0) << 4));
        intx4 af1 = *(const intx4*)(cb +        pa1 + ((c ^ sa1) << 4));
        intx4 bf0 = *(const intx4*)(cb + 8192 + pb0 + ((c ^ sb0) << 4));
        intx4 bf1 = *(const intx4*)(cb + 8192 + pb1 + ((c ^ sb1) << 4));
        acc[0][0] = __builtin_amdgcn_mfma_i32_32x32x32_i8(af0, bf0, acc[0][0], 0, 0, 0);
        acc[0][1] = __builtin_amdgcn_mfma_i32_32x32x32_i8(af0, bf1, acc[0][1], 0, 0, 0);
        acc[1][0] = __builtin_amdgcn_mfma_i32_32x32x32_i8(af1, bf0, acc[1][0], 0, 0, 0);
        acc[1][1] = __builtin_amdgcn_mfma_i32_32x32x32_i8(af1, bf1, acc[1][1], 0, 0, 0);
      }
      __syncthreads();
    }
#undef STAGE4

    int vmin = 0x7fffffff;
#pragma unroll
    for (int ti = 0; ti < 2; ti++)
#pragma unroll
      for (int tj = 0; tj < 2; tj++)
#pragma unroll
        for (int r = 0; r < 16; r++) vmin = min(vmin, acc[ti][tj][r]);
#pragma unroll
    for (int m_ = 32; m_ >= 1; m_ >>= 1)
      vmin = min(vmin, __shfl_xor(vmin, m_));
    if (lane == 0) iredbuf[w] = vmin;
    __syncthreads();
    if (tid == 0) {
      int mn = iredbuf[0];
      for (int i = 1; i < 4; i++) mn = min(mn, iredbuf[i]);
      ipart[pi] = mn;
      atomicMin(&ctrl[2], mn);
    }
  } else {
    // ---- bf16 diagonal path (exact), BK=128, 32 KB of smem ----
    if (tid == 0) ipart[pi] = 0x7fffffff;        // never flagged
    unsigned short* lA = (unsigned short*)&smem[0][0];
    floatx16 acc[2][2];
#pragma unroll
    for (int i = 0; i < 2; i++)
#pragma unroll
      for (int j = 0; j < 2; j++)
#pragma unroll
        for (int r = 0; r < 16; r++) acc[i][j][r] = 0.f;

    const int rowBase = tr * 128;

    for (int kb = 0; kb < 4; kb++) {
      const int kBase = kb * 128;
#pragma unroll
      for (int j = 0; j < 8; j++) {
        int p   = (w * 8 + j) * 64 + lane;        // 0..2047 chunk id
        int row = p >> 4, c16 = p & 15;
        int sc = swzd(row, c16);
        const unsigned short* gA =
            E + (size_t)(rowBase + row) * DIM + kBase + sc * 8;
        __builtin_amdgcn_global_load_lds((const AS1 unsigned int*)gA,
                                         (AS3 unsigned int*)(lA + p * 8), 16, 0, 0);
      }
      __syncthreads();

#pragma unroll
      for (int ks = 0; ks < 8; ks++) {
        bf16x8 af[2], bfv[2];
        const int c16 = ks * 2 + kg;
#pragma unroll
        for (int t = 0; t < 2; t++) {
          int ra = wr * 64 + t * 32 + l31;
          int rb = wc * 64 + t * 32 + l31;
          af[t]  = *(const bf16x8*)(lA + ra * 128 + swzd(ra, c16) * 8);
          bfv[t] = *(const bf16x8*)(lA + rb * 128 + swzd(rb, c16) * 8);
        }
#pragma unroll
        for (int ti = 0; ti < 2; ti++)
#pragma unroll
          for (int tj = 0; tj < 2; tj++)
            acc[ti][tj] = __builtin_amdgcn_mfma_f32_32x32x16_bf16(
                af[ti], bfv[tj], acc[ti][tj], 0, 0, 0);
      }
      __syncthreads();
    }

    float vmin = 3.4e38f, vmax = -3.4e38f;
#pragma unroll
    for (int ti = 0; ti < 2; ti++)
#pragma unroll
      for (int tj = 0; tj < 2; tj++)
#pragma unroll
        for (int r = 0; r < 16; r++) {
          float v = acc[ti][tj][r];
          vmin = fminf(vmin, v);
          vmax = fmaxf(vmax, v);
        }
#pragma unroll
    for (int m_ = 32; m_ >= 1; m_ >>= 1) {
      vmin = fminf(vmin, __shfl_xor(vmin, m_));
      vmax = fmaxf(vmax, __shfl_xor(vmax, m_));
    }
    if (lane == 0) redbuf[w] = make_float2(vmin, vmax);
    __syncthreads();
    if (tid == 0) {
      float mn = redbuf[0].x, mx = redbuf[0].y;
      for (int i = 1; i < 4; i++) {
        mn = fminf(mn, redbuf[i].x);
        mx = fmaxf(mx, redbuf[i].y);
      }
      atomicMin(&ctrl[0], fkey(mn));
      atomicMax(&ctrl[1], fkey(mx));  // global max is diagonal (Cauchy-Schwarz)
    }

    float* Bout = diagblocks + (size_t)tr * (128 * 128);
#pragma unroll
    for (int ti = 0; ti < 2; ti++) {
#pragma unroll
      for (int tj = 0; tj < 2; tj++) {
        int cbase = wc * 64 + tj * 32 + l31;      // C/D: col = lane & 31
#pragma unroll
        for (int r = 0; r < 16; r++) {
          int row = wr * 64 + ti * 32 + (r & 3) + 8 * (r >> 2) + 4 * kg;
          Bout[row * 128 + cbase] = acc[ti][tj][r];
        }
      }
    }
  }
}

// ---- kernel 3: self-flagged bf16 refine (exact min of flagged tiles) -------
__global__ __launch_bounds__(256) void k_refine(
    const unsigned short* __restrict__ E,
    const int* __restrict__ ipart, int* __restrict__ ctrl) {
  const int pi = blockIdx.x;
  if (ipart[pi] > ctrl[2] + MARGIN_I) return;     // block-uniform
  const int tr = pi / 65, x = pi % 65;
  if (x == 64) return;                            // diag: exact already
  // same wrapped-column map as k_gemm
  const int tcw = (tr + 1 + x) & 127;
  const int a = min(tr, tcw), b = max(tr, tcw);

  const int tid = threadIdx.x;
  __shared__ __align__(16) unsigned short lA[128 * 64];
  __shared__ __align__(16) unsigned short lB[128 * 64];
  __shared__ float redbuf[4];

  const int w = tid >> 6, lane = tid & 63;
  const int wr = w >> 1, wc = w & 1;
  const int l31 = lane & 31;
  const int kg  = lane >> 5;

  floatx16 acc[2][2];
#pragma unroll
  for (int i = 0; i < 2; i++)
#pragma unroll
    for (int j = 0; j < 2; j++)
#pragma unroll
      for (int r = 0; r < 16; r++) acc[i][j][r] = 0.f;

  const int rowBaseA = a * 128;
  const int rowBaseB = b * 128;

  for (int kb = 0; kb < 8; kb++) {              // BK=64
    const int kBase = kb * 64;
#pragma unroll
    for (int j = 0; j < 4; j++) {
      int cb  = (w * 4 + j) * 64;
      int p   = cb + lane;
      int row = p >> 3, c8 = p & 7;
      int sc8 = swz8(row, c8);
      const unsigned short* gA = E + (size_t)(rowBaseA + row) * DIM + kBase + sc8 * 8;
      const unsigned short* gB = E + (size_t)(rowBaseB + row) * DIM + kBase + sc8 * 8;
      __builtin_amdgcn_global_load_lds((const AS1 unsigned int*)gA,
                                       (AS3 unsigned int*)(lA + cb * 8), 16, 0, 0);
      __builtin_amdgcn_global_load_lds((const AS1 unsigned int*)gB,
                                       (AS3 unsigned int*)(lB + cb * 8), 16, 0, 0);
    }
    __syncthreads();

#pragma unroll
    for (int ks = 0; ks < 4; ks++) {
      bf16x8 af[2], bfv[2];
      const int c8 = ks * 2 + kg;
#pragma unroll
      for (int t = 0; t < 2; t++) {
        int ra = wr * 64 + t * 32 + l31;
        int rb = wc * 64 + t * 32 + l31;
        af[t]  = *(const bf16x8*)(lA + (ra * 8 + swz8(ra, c8)) * 8);
        bfv[t] = *(const bf16x8*)(lB + (rb * 8 + swz8(rb, c8)) * 8);
      }
#pragma unroll
      for (int ti = 0; ti < 2; ti++)
#pragma unroll
        for (int tj = 0; tj < 2; tj++)
          acc[ti][tj] = __builtin_amdgcn_mfma_f32_32x32x16_bf16(
              af[ti], bfv[tj], acc[ti][tj], 0, 0, 0);
    }
    __syncthreads();
  }

  float vmin = 3.4e38f;
#pragma unroll
  for (int ti = 0; ti < 2; ti++)
#pragma unroll
    for (int tj = 0; tj < 2; tj++)
#pragma unroll
      for (int r = 0; r < 16; r++) vmin = fminf(vmin, acc[ti][tj][r]);
#pragma unroll
  for (int m_ = 32; m_ >= 1; m_ >>= 1)
    vmin = fminf(vmin, __shfl_xor(vmin, m_));
  if (lane == 0) redbuf[w] = vmin;
  __syncthreads();
  if (tid == 0) {
    float mn = redbuf[0];
    for (int i = 1; i < 4; i++) mn = fminf(mn, redbuf[i]);
    atomicMin(&ctrl[0], fkey(mn));
  }
}

// ---- kernel 4: gather + normalize ------------------------------------------
__global__ __launch_bounds__(256) void k_gather(
    const int* __restrict__ rix, const int* __restrict__ cix,
    const float* __restrict__ blocks, const int* __restrict__ ctrl,
    float* __restrict__ out, int n) {
  int i = blockIdx.x * blockDim.x + threadIdx.x;
  if (i >= n) return;
  float m   = funkey(ctrl[0]);
  float M   = funkey(ctrl[1]);
  float inv = 1.0f / (M - m + 1e-7f);
  int r = rix[i], c = cix[i];
  int g = r >> 7;
  float v = blocks[((size_t)g << 14) + ((r & 127) << 7) + (c & 127)];
  out[i] = (v - m) * inv;
}

// ---------------------------------------------------------------------------
extern "C" void kernel_launch(void* const* d_in, const int* in_sizes, int n_in,
                              void* d_out, int out_size, void* d_ws, size_t ws_size,
                              hipStream_t stream) {
  const float* emb = (const float*)d_in[0];
  const int* rix   = (const int*)d_in[1];
  const int* cix   = (const int*)d_in[2];

  char* ws = (char*)d_ws;
  int* ctrl           = (int*)ws;                            // 12 B (pad 256)
  unsigned short* Ebf = (unsigned short*)(ws + 256);         // 16 MB
  char* Eq            = (char*)(ws + 256 + (16u << 20));     // 8 MB
  float* diagblocks   = (float*)(ws + 256 + (24u << 20));    // 8 MB
  int* ipart          = (int*)(ws + 256 + (32u << 20));      // 33 KB

  int n4 = in_sizes[0] / 4;            // 16384*512 / 4

  k_convert<<<(n4 + 255) / 256, 256, 0, stream>>>(emb, Ebf, Eq, ctrl, n4);

  k_gemm<<<dim3(GX, 128), 256, 0, stream>>>(Eq, Ebf, ipart, diagblocks, ctrl);

  k_refine<<<NPAIRIDX, 256, 0, stream>>>(Ebf, ipart, ctrl);

  k_gather<<<(out_size + 255) / 256, 256, 0, stream>>>(rix, cix, diagblocks,
                                                       ctrl, (float*)d_out,
                                                       out_size);
}

// Round 7
// 190.673 us; speedup vs baseline: 1.1520x; 1.1520x over previous
//
#include <hip/hip_runtime.h>
#include <hip/hip_bf16.h>
#include <stdint.h>

// ---------------------------------------------------------------------------
// LinkPredictor: out = minmax_norm(E @ E^T)[block-diag strict upper triangle]
// N=16384 (128 graphs x 128), D=512.
// R17: occupancy x2 at IDENTICAL traffic. R16 confounded occupancy (x2, good)
// with traffic (x4, bad: wrapped map killed pairing; 156MB fetch) and a worse
// per-wave LDS ratio (64x64). R17 keeps R15's pair-strip block (128x256 out,
// A+B0+B1 staged once, 39MB fetch) but with 8 waves of 512 threads:
// per-wave 64x64 -> acc[2][2] = 64 AGPR, ~115 regs total ->
// __launch_bounds__(512,4): 4 waves/SIMD, 2 blocks/CU, 16 waves/CU (2x R15).
// Staging: 512 threads = one 8KB plane per gload_lds, 3/thread/K-tile.
// i8 LDS layout = R14/R15's measured-zero map:
//   granule(row,c4) = qswap(row)*4 + (c4 ^ sfun(row)), qswap = swap bits 0,2.
// K-loop: 2-phase issue-early (proven race-free R14/R15; counted-vmcnt null).
// Diag path: 8-wave 64x32/wave. Refine reverted to R15 pair version.
// Convert/gather unchanged.
// ---------------------------------------------------------------------------

typedef __attribute__((ext_vector_type(8))) __bf16 bf16x8;
typedef __attribute__((ext_vector_type(16))) float floatx16;
typedef __attribute__((ext_vector_type(4))) int intx4;
typedef __attribute__((ext_vector_type(16))) int intx16;

#define AS1 __attribute__((address_space(1)))
#define AS3 __attribute__((address_space(3)))

static constexpr int DIM      = 512;
static constexpr int NTILE    = 128;
static constexpr int GX       = 72;         // padded grid x (multiple of 8)
static constexpr int NPAIRIDX = 65 * 128;   // pair-slot space (x=64 -> diag)
static constexpr float QS     = 19.5f;      // i8 quant scale
static constexpr int MARGIN_I = 3042;       // 8 sims-units * QS^2

// ctrl: [0] fkey_min [1] fkey_max [2] i8 gmin

static __device__ __forceinline__ unsigned short f2bf_rne(float f) {
  unsigned int u = __float_as_uint(f);
  u += 0x7fffu + ((u >> 16) & 1u);
  return (unsigned short)(u >> 16);
}
static __device__ __forceinline__ int fkey(float f) {
  int s = __float_as_int(f);
  return s >= 0 ? s : (s ^ 0x7fffffff);
}
static __device__ __forceinline__ float funkey(int k) {
  return __int_as_float(k >= 0 ? k : (k ^ 0x7fffffff));
}
// bf16 tile, BK=128 (diag): 16 chunks(16B)/row
static __device__ __forceinline__ int swzd(int row, int c16) {
  return c16 ^ (row & 15);
}
// bf16 tile, BK=64 (refine): 8 chunks(16B)/row
static __device__ __forceinline__ int swz8(int row, int c8) {
  return c8 ^ (row & 7);
}
// i8 BK=64 layout helpers: q = swap bits 0,2 (involution)
static __device__ __forceinline__ int qswap(int v) {
  return (v & 0x7A) | ((v & 1) << 2) | ((v >> 2) & 1);
}
static __device__ __forceinline__ int sfun(int row) {
  return (row & 3) ^ ((row >> 3) & 3);
}

// ---- kernel 1: fp32 -> bf16 + i8, init ctrl --------------------------------
__global__ void k_convert(const float* __restrict__ in,
                          unsigned short* __restrict__ bf,
                          char* __restrict__ q,
                          int* __restrict__ ctrl, int n4) {
  int i = blockIdx.x * blockDim.x + threadIdx.x;
  if (i == 0) {
    ctrl[0] = 0x7fffffff; ctrl[1] = (int)0x80000000;
    ctrl[2] = 0x7fffffff;
  }
  if (i >= n4) return;
  float4 v = ((const float4*)in)[i];
  ushort4 o;
  o.x = f2bf_rne(v.x); o.y = f2bf_rne(v.y);
  o.z = f2bf_rne(v.z); o.w = f2bf_rne(v.w);
  ((ushort4*)bf)[i] = o;
  int qx = __float2int_rn(v.x * QS), qy = __float2int_rn(v.y * QS);
  int qz = __float2int_rn(v.z * QS), qw = __float2int_rn(v.w * QS);
  char4 c;
  c.x = (char)min(127, max(-127, qx));
  c.y = (char)min(127, max(-127, qy));
  c.z = (char)min(127, max(-127, qz));
  c.w = (char)min(127, max(-127, qw));
  ((char4*)q)[i] = c;
}

// ---- kernel 2: GEMM --------------------------------------------------------
// grid (72, 128) x 512 threads: x<64 -> i8 pair strip 128x256 at
// (tr=y, tc={2x,2x+1}); x==64 -> bf16 exact diagonal tile tr; x>64 -> pad.
__global__ __launch_bounds__(512, 4) void k_gemm(
    const char* __restrict__ Eq,
    const unsigned short* __restrict__ E,
    int* __restrict__ ipart,
    float* __restrict__ diagblocks,
    int* __restrict__ ctrl) {
  const int x  = blockIdx.x;
  const int tr = blockIdx.y;
  if (x > 64) return;                      // XCD-alignment padding
  const int pi = tr * 65 + x;

  const int tid = threadIdx.x;
  // i8 path: 2 buffers x {A[8KB], B0[8KB], B1[8KB]} = 48 KB.
  // Diag path reuses first 32 KB as one bf16 tile.
  __shared__ __align__(16) char smem[2][24576];
  __shared__ float2 redbuf[8];
  __shared__ int iredbuf[8];

  const int w = tid >> 6, lane = tid & 63;
  const int l31 = lane & 31;
  const int kg  = lane >> 5;

  if (x < 64) {
    const int tc1 = 2 * x + 1;
    if (tc1 <= tr) {                 // pair entirely at/below diagonal
      if (tid == 0) ipart[pi] = 0x7fffffff;
      return;
    }
    const int tc0 = (2 * x > tr) ? 2 * x : tc1;   // dup tc1 if tc0 not off-diag

    const int rowA  = tr  * 128;
    const int rowB0 = tc0 * 128;
    const int rowB1 = tc1 * 128;

    // 8-wave decomposition of the 128x256 output: wr = w>>2 (row half),
    // wc = w&3 (64-col quarter; wc>>1 selects B plane, wc&1 the half inside).
    const int wr = w >> 2;
    const int wcq = w & 3;
    const int bplane = 8192 + (wcq >> 1) * 8192;   // B0 or B1 plane offset

    intx16 acc[2][2];                // 64 AGPR
#pragma unroll
    for (int i = 0; i < 2; i++)
#pragma unroll
      for (int j = 0; j < 2; j++)
#pragma unroll
        for (int r = 0; r < 16; r++) acc[i][j][r] = 0;

    // Stage one BK=64 K-tile (A,B0,B1) into buffer bb: 3 loads/thread
    // (512 threads = exactly one 8KB plane each). LDS dest linear (p*16).
    // Granule p = qswap(row)*4 + (c4 ^ sfun(row)): quad q_=p>>2 -> row =
    // qswap(q_) (involution), c4 = (p&3)^sfun(row). Lanes 4k..4k+3 share a
    // row -> one 64B global line per quad (coalesced); bank signature =
    // R10's measured-zero pattern on the read side.
#define STAGE3(bb, kt) do {                                                   \
    int p_   = tid;                                                           \
    int q_   = p_ >> 2;                                                       \
    int row_ = qswap(q_);                                                     \
    int off_ = (kt) * 64 + (((p_ & 3) ^ sfun(row_)) * 16);                    \
    char* d_ = smem[bb] + p_ * 16;                                            \
    __builtin_amdgcn_global_load_lds(                                         \
        (const AS1 unsigned int*)(Eq + (size_t)(rowA + row_) * DIM + off_),   \
        (AS3 unsigned int*)d_, 16, 0, 0);                                     \
    __builtin_amdgcn_global_load_lds(                                         \
        (const AS1 unsigned int*)(Eq + (size_t)(rowB0 + row_) * DIM + off_),  \
        (AS3 unsigned int*)(d_ + 8192), 16, 0, 0);                            \
    __builtin_amdgcn_global_load_lds(                                         \
        (const AS1 unsigned int*)(Eq + (size_t)(rowB1 + row_) * DIM + off_),  \
        (AS3 unsigned int*)(d_ + 16384), 16, 0, 0);                           \
  } while (0)

    const int ra0 = wr * 64 + l31,        ra1 = wr * 64 + 32 + l31;
    const int rb0 = (wcq & 1) * 64 + l31, rb1 = (wcq & 1) * 64 + 32 + l31;
    // per-thread read offsets: byte addr = qswap(row)*64 + ((c4^sfun(row))<<4)
    const int pa0 = qswap(ra0) * 64, sa0 = sfun(ra0);
    const int pa1 = qswap(ra1) * 64, sa1 = sfun(ra1);
    const int pb0 = qswap(rb0) * 64, sb0 = sfun(rb0);
    const int pb1 = qswap(rb1) * 64, sb1 = sfun(rb1);

    STAGE3(0, 0);
    __syncthreads();

#pragma unroll
    for (int kt = 0; kt < 8; kt++) {               // K = 512 = 8 * BK(64)
      // Issue next tile's loads FIRST - they fly during this tile's compute.
      if (kt + 1 < 8) STAGE3((kt + 1) & 1, kt + 1);
      const char* cb = smem[kt & 1];
#pragma unroll
      for (int ks = 0; ks < 2; ks++) {             // 2 k-steps of 32
        const int c = ks * 2 + kg;
        intx4 af0 = *(const intx4*)(cb +           pa0 + ((c ^ sa0) << 4));
        intx4 af1 = *(const intx4*)(cb +           pa1 + ((c ^ sa1) << 4));
        intx4 bf0 = *(const intx4*)(cb + bplane +  pb0 + ((c ^ sb0) << 4));
        intx4 bf1 = *(const intx4*)(cb + bplane +  pb1 + ((c ^ sb1) << 4));
        acc[0][0] = __builtin_amdgcn_mfma_i32_32x32x32_i8(af0, bf0, acc[0][0], 0, 0, 0);
        acc[0][1] = __builtin_amdgcn_mfma_i32_32x32x32_i8(af0, bf1, acc[0][1], 0, 0, 0);
        acc[1][0] = __builtin_amdgcn_mfma_i32_32x32x32_i8(af1, bf0, acc[1][0], 0, 0, 0);
        acc[1][1] = __builtin_amdgcn_mfma_i32_32x32x32_i8(af1, bf1, acc[1][1], 0, 0, 0);
      }
      __syncthreads();
    }
#undef STAGE3

    int vmin = 0x7fffffff;
#pragma unroll
    for (int ti = 0; ti < 2; ti++)
#pragma unroll
      for (int tj = 0; tj < 2; tj++)
#pragma unroll
        for (int r = 0; r < 16; r++) vmin = min(vmin, acc[ti][tj][r]);
#pragma unroll
    for (int m_ = 32; m_ >= 1; m_ >>= 1)
      vmin = min(vmin, __shfl_xor(vmin, m_));
    if (lane == 0) iredbuf[w] = vmin;
    __syncthreads();
    if (tid == 0) {
      int mn = iredbuf[0];
      for (int i = 1; i < 8; i++) mn = min(mn, iredbuf[i]);
      ipart[pi] = mn;
      atomicMin(&ctrl[2], mn);
    }
  } else {
    // ---- bf16 diagonal path (exact), BK=128, 32 KB of smem, 8 waves ----
    if (tid == 0) ipart[pi] = 0x7fffffff;        // never flagged
    unsigned short* lA = (unsigned short*)&smem[0][0];
    // per-wave 64x32: wr = w>>2 row half, wcq = w&3 col 32-quarter
    const int wr = w >> 2, wcq = w & 3;
    floatx16 acc[2];
#pragma unroll
    for (int t = 0; t < 2; t++)
#pragma unroll
      for (int r = 0; r < 16; r++) acc[t][r] = 0.f;

    const int rowBase = tr * 128;

    for (int kb = 0; kb < 4; kb++) {
      const int kBase = kb * 128;
#pragma unroll
      for (int j = 0; j < 4; j++) {
        int p   = j * 512 + tid;                  // 0..2047 chunk id
        int row = p >> 4, c16 = p & 15;
        int sc = swzd(row, c16);
        const unsigned short* gA =
            E + (size_t)(rowBase + row) * DIM + kBase + sc * 8;
        __builtin_amdgcn_global_load_lds((const AS1 unsigned int*)gA,
                                         (AS3 unsigned int*)(lA + p * 8), 16, 0, 0);
      }
      __syncthreads();

#pragma unroll
      for (int ks = 0; ks < 8; ks++) {
        bf16x8 af[2], bfv;
        const int c16 = ks * 2 + kg;
#pragma unroll
        for (int t = 0; t < 2; t++) {
          int ra = wr * 64 + t * 32 + l31;
          af[t]  = *(const bf16x8*)(lA + ra * 128 + swzd(ra, c16) * 8);
        }
        {
          int rb = wcq * 32 + l31;
          bfv = *(const bf16x8*)(lA + rb * 128 + swzd(rb, c16) * 8);
        }
#pragma unroll
        for (int t = 0; t < 2; t++)
          acc[t] = __builtin_amdgcn_mfma_f32_32x32x16_bf16(
              af[t], bfv, acc[t], 0, 0, 0);
      }
      __syncthreads();
    }

    float vmin = 3.4e38f, vmax = -3.4e38f;
#pragma unroll
    for (int t = 0; t < 2; t++)
#pragma unroll
      for (int r = 0; r < 16; r++) {
        float v = acc[t][r];
        vmin = fminf(vmin, v);
        vmax = fmaxf(vmax, v);
      }
#pragma unroll
    for (int m_ = 32; m_ >= 1; m_ >>= 1) {
      vmin = fminf(vmin, __shfl_xor(vmin, m_));
      vmax = fmaxf(vmax, __shfl_xor(vmax, m_));
    }
    if (lane == 0) redbuf[w] = make_float2(vmin, vmax);
    __syncthreads();
    if (tid == 0) {
      float mn = redbuf[0].x, mx = redbuf[0].y;
      for (int i = 1; i < 8; i++) {
        mn = fminf(mn, redbuf[i].x);
        mx = fmaxf(mx, redbuf[i].y);
      }
      atomicMin(&ctrl[0], fkey(mn));
      atomicMax(&ctrl[1], fkey(mx));  // global max is diagonal (Cauchy-Schwarz)
    }

    float* Bout = diagblocks + (size_t)tr * (128 * 128);
    const int cbase = wcq * 32 + l31;             // C/D: col = lane & 31
#pragma unroll
    for (int t = 0; t < 2; t++) {
#pragma unroll
      for (int r = 0; r < 16; r++) {
        int row = wr * 64 + t * 32 + (r & 3) + 8 * (r >> 2) + 4 * kg;
        Bout[row * 128 + cbase] = acc[t][r];
      }
    }
  }
}

// ---- kernel 3: self-flagged bf16 refine (exact min of flagged pairs) -------
__global__ __launch_bounds__(256) void k_refine(
    const unsigned short* __restrict__ E,
    const int* __restrict__ ipart, int* __restrict__ ctrl) {
  const int pi = blockIdx.x;
  if (ipart[pi] > ctrl[2] + MARGIN_I) return;     // block-uniform
  const int tr = pi / 65, x = pi % 65;
  if (x == 64) return;                            // diag: exact already

  const int tid = threadIdx.x;
  __shared__ __align__(16) unsigned short lA[128 * 64];
  __shared__ __align__(16) unsigned short lB[128 * 64];
  __shared__ float redbuf[4];

  const int w = tid >> 6, lane = tid & 63;
  const int wr = w >> 1, wc = w & 1;
  const int l31 = lane & 31;
  const int kg  = lane >> 5;

  for (int s = 0; s < 2; s++) {
    const int tc = 2 * x + s;
    if (tc <= tr) continue;

    floatx16 acc[2][2];
#pragma unroll
    for (int i = 0; i < 2; i++)
#pragma unroll
      for (int j = 0; j < 2; j++)
#pragma unroll
        for (int r = 0; r < 16; r++) acc[i][j][r] = 0.f;

    const int rowBaseA = tr * 128;
    const int rowBaseB = tc * 128;

    for (int kb = 0; kb < 8; kb++) {              // BK=64
      const int kBase = kb * 64;
#pragma unroll
      for (int j = 0; j < 4; j++) {
        int cb  = (w * 4 + j) * 64;
        int p   = cb + lane;
        int row = p >> 3, c8 = p & 7;
        int sc8 = swz8(row, c8);
        const unsigned short* gA = E + (size_t)(rowBaseA + row) * DIM + kBase + sc8 * 8;
        const unsigned short* gB = E + (size_t)(rowBaseB + row) * DIM + kBase + sc8 * 8;
        __builtin_amdgcn_global_load_lds((const AS1 unsigned int*)gA,
                                         (AS3 unsigned int*)(lA + cb * 8), 16, 0, 0);
        __builtin_amdgcn_global_load_lds((const AS1 unsigned int*)gB,
                                         (AS3 unsigned int*)(lB + cb * 8), 16, 0, 0);
      }
      __syncthreads();

#pragma unroll
      for (int ks = 0; ks < 4; ks++) {
        bf16x8 af[2], bfv[2];
        const int c8 = ks * 2 + kg;
#pragma unroll
        for (int t = 0; t < 2; t++) {
          int ra = wr * 64 + t * 32 + l31;
          int rb = wc * 64 + t * 32 + l31;
          af[t]  = *(const bf16x8*)(lA + (ra * 8 + swz8(ra, c8)) * 8);
          bfv[t] = *(const bf16x8*)(lB + (rb * 8 + swz8(rb, c8)) * 8);
        }
#pragma unroll
        for (int ti = 0; ti < 2; ti++)
#pragma unroll
          for (int tj = 0; tj < 2; tj++)
            acc[ti][tj] = __builtin_amdgcn_mfma_f32_32x32x16_bf16(
                af[ti], bfv[tj], acc[ti][tj], 0, 0, 0);
      }
      __syncthreads();
    }

    float vmin = 3.4e38f;
#pragma unroll
    for (int ti = 0; ti < 2; ti++)
#pragma unroll
      for (int tj = 0; tj < 2; tj++)
#pragma unroll
        for (int r = 0; r < 16; r++) vmin = fminf(vmin, acc[ti][tj][r]);
#pragma unroll
    for (int m_ = 32; m_ >= 1; m_ >>= 1)
      vmin = fminf(vmin, __shfl_xor(vmin, m_));
    if (lane == 0) redbuf[w] = vmin;
    __syncthreads();
    if (tid == 0) {
      float mn = redbuf[0];
      for (int i = 1; i < 4; i++) mn = fminf(mn, redbuf[i]);
      atomicMin(&ctrl[0], fkey(mn));
    }
    __syncthreads();
  }
}

// ---- kernel 4: gather + normalize ------------------------------------------
__global__ __launch_bounds__(256) void k_gather(
    const int* __restrict__ rix, const int* __restrict__ cix,
    const float* __restrict__ blocks, const int* __restrict__ ctrl,
    float* __restrict__ out, int n) {
  int i = blockIdx.x * blockDim.x + threadIdx.x;
  if (i >= n) return;
  float m   = funkey(ctrl[0]);
  float M   = funkey(ctrl[1]);
  float inv = 1.0f / (M - m + 1e-7f);
  int r = rix[i], c = cix[i];
  int g = r >> 7;
  float v = blocks[((size_t)g << 14) + ((r & 127) << 7) + (c & 127)];
  out[i] = (v - m) * inv;
}

// ---------------------------------------------------------------------------
extern "C" void kernel_launch(void* const* d_in, const int* in_sizes, int n_in,
                              void* d_out, int out_size, void* d_ws, size_t ws_size,
                              hipStream_t stream) {
  const float* emb = (const float*)d_in[0];
  const int* rix   = (const int*)d_in[1];
  const int* cix   = (const int*)d_in[2];

  char* ws = (char*)d_ws;
  int* ctrl           = (int*)ws;                            // 12 B (pad 256)
  unsigned short* Ebf = (unsigned short*)(ws + 256);         // 16 MB
  char* Eq            = (char*)(ws + 256 + (16u << 20));     // 8 MB
  float* diagblocks   = (float*)(ws + 256 + (24u << 20));    // 8 MB
  int* ipart          = (int*)(ws + 256 + (32u << 20));      // 33 KB

  int n4 = in_sizes[0] / 4;            // 16384*512 / 4

  k_convert<<<(n4 + 255) / 256, 256, 0, stream>>>(emb, Ebf, Eq, ctrl, n4);

  k_gemm<<<dim3(GX, 128), 512, 0, stream>>>(Eq, Ebf, ipart, diagblocks, ctrl);

  k_refine<<<NPAIRIDX, 256, 0, stream>>>(Ebf, ipart, ctrl);

  k_gather<<<(out_size + 255) / 256, 256, 0, stream>>>(rix, cix, diagblocks,
                                                       ctrl, (float*)d_out,
                                                       out_size);
}